// Round 5
// baseline (125.678 us; speedup 1.0000x reference)
//
#include <hip/hip_runtime.h>
#include <cstdint>
#include <cstddef>

// Problem constants
#define Bb   64
#define Ll   2048
#define Mm   128
#define ROWS (Bb * Ll)          // 131072
#define OUTC 768                // 6*M

typedef __attribute__((ext_vector_type(4))) float  f32x4;
typedef __attribute__((ext_vector_type(8))) short  bf16x8;   // storage for 8 bf16
typedef __bf16 bf16x8b __attribute__((ext_vector_type(8)));  // builtin operand type

__device__ __forceinline__ float rcp_(float x) {
#if __has_builtin(__builtin_amdgcn_rcpf)
    return __builtin_amdgcn_rcpf(x);
#else
    return 1.0f / x;
#endif
}
__device__ __forceinline__ float sigmoid_(float x) {
    return rcp_(1.0f + __expf(-x));
}
__device__ __forceinline__ float tanh_(float x) {
    float ax = fabsf(x);
    float r  = __expf(-2.0f * ax);
    float t  = (1.0f - r) * rcp_(1.0f + r);
    return x < 0.0f ? -t : t;
}
// f32 -> bf16 bits, round-to-nearest-even
__device__ __forceinline__ short f2bf(float f) {
    uint32_t u = __builtin_bit_cast(uint32_t, f);
    u = (u + 0x7FFFu + ((u >> 16) & 1u)) >> 16;
    return (short)(u & 0xFFFFu);
}

// ---------------------------------------------------------------------------
// ws layout:
//   floats [0 .. 32768)     : state: [0]=cph,[1]=cpc,[2]=hph,[3]=hpc (64,128)
//   shorts [65536 .. 98304) : Wbf [gate*128+col][k] bf16, gate 0=Wc 1=Wo
// ---------------------------------------------------------------------------

// Kernel 1: collapsed tree state (both children identical => one (B,M) state
// iterated depth-1 times), then leaf() on final h and c. k-split 4-way across
// 512 threads with LDS partial reduction; wprep fused.
__global__ __launch_bounds__(512)
void state_kernel(const float* __restrict__ root_c, const float* __restrict__ root_h,
                  const float* __restrict__ Wi, const float* __restrict__ bi,
                  const float* __restrict__ Wf, const float* __restrict__ bfv,
                  const float* __restrict__ Wu, const float* __restrict__ bu,
                  const float* __restrict__ Wc, const float* __restrict__ bc,
                  const float* __restrict__ Wo, const float* __restrict__ bo,
                  float* __restrict__ ws, short* __restrict__ wbf)
{
    const int b   = blockIdx.x;
    const int tid = threadIdx.x;
    const int m   = tid & 127;
    const int q   = tid >> 7;            // 0..3
    const int k0  = q * 32;

    __shared__ float h_sh[Mm];
    __shared__ float c_sh[Mm];
    __shared__ float part[4][4][Mm];     // [slot][q][m]

    // fused wprep: 64 blocks x 512 threads = 32768 elems, 1 per thread
    {
        int idx  = b * 512 + tid;
        int gate = idx >> 14;
        int col  = (idx >> 7) & 127;
        int k    = idx & 127;
        const float* W = gate ? Wo : Wc;
        wbf[idx] = f2bf(W[k * Mm + col]);
    }

    float c = 0.f;
    if (q == 0) {
        c = root_c[b * Mm + m];
        h_sh[m] = root_h[b * Mm + m];
    }
    __syncthreads();

    const float bi_m = bi[m], bf_m = bfv[m], bu_m = bu[m];

    for (int it = 0; it < 10; ++it) {        // depth-1 = 10
        float di0 = 0.f, di1 = 0.f, df0 = 0.f, df1 = 0.f, du0 = 0.f, du1 = 0.f;
        #pragma unroll
        for (int kk = 0; kk < 32; kk += 2) {
            int k = k0 + kk;
            float h0 = h_sh[k], h1 = h_sh[k + 1];
            di0 = fmaf(h0, Wi[k * Mm + m], di0);
            di1 = fmaf(h1, Wi[(k + 1) * Mm + m], di1);
            df0 = fmaf(h0, Wf[k * Mm + m], df0);
            df1 = fmaf(h1, Wf[(k + 1) * Mm + m], df1);
            du0 = fmaf(h0, Wu[k * Mm + m], du0);
            du1 = fmaf(h1, Wu[(k + 1) * Mm + m], du1);
        }
        part[0][q][m] = di0 + di1;
        part[1][q][m] = df0 + df1;
        part[2][q][m] = du0 + du1;
        __syncthreads();
        if (q == 0) {
            float di = (part[0][0][m] + part[0][1][m]) + (part[0][2][m] + part[0][3][m]);
            float df = (part[1][0][m] + part[1][1][m]) + (part[1][2][m] + part[1][3][m]);
            float du = (part[2][0][m] + part[2][1][m]) + (part[2][2][m] + part[2][3][m]);
            float ig = sigmoid_(di + bi_m);
            float fg = sigmoid_(df + bf_m);
            float ug = tanh_(du + bu_m);
            c = ig * ug + fg * c;
            h_sh[m] = tanh_(c);
        }
        __syncthreads();
    }
    if (q == 0) c_sh[m] = c;
    __syncthreads();

    float dch = 0.f, doh = 0.f, dcc = 0.f, doc = 0.f;
    #pragma unroll
    for (int kk = 0; kk < 32; ++kk) {
        int k = k0 + kk;
        float hk = h_sh[k], ck = c_sh[k];
        float wc = Wc[k * Mm + m], wo = Wo[k * Mm + m];
        dch = fmaf(hk, wc, dch);
        doh = fmaf(hk, wo, doh);
        dcc = fmaf(ck, wc, dcc);
        doc = fmaf(ck, wo, doc);
    }
    part[0][q][m] = dch;
    part[1][q][m] = doh;
    part[2][q][m] = dcc;
    part[3][q][m] = doc;
    __syncthreads();
    if (q == 0) {
        float Dch = (part[0][0][m] + part[0][1][m]) + (part[0][2][m] + part[0][3][m]);
        float Doh = (part[1][0][m] + part[1][1][m]) + (part[1][2][m] + part[1][3][m]);
        float Dcc = (part[2][0][m] + part[2][1][m]) + (part[2][2][m] + part[2][3][m]);
        float Doc = (part[3][0][m] + part[3][1][m]) + (part[3][2][m] + part[3][3][m]);
        const float bcm = bc[m], bom = bo[m];
        float cph = Dch + bcm;
        float cpc = Dcc + bcm;
        float hph = sigmoid_(Doh + bom) * tanh_(cph);
        float hpc = sigmoid_(Doc + bom) * tanh_(cpc);
        ws[0 * Bb * Mm + b * Mm + m] = cph;
        ws[1 * Bb * Mm + b * Mm + m] = cpc;
        ws[2 * Bb * Mm + b * Mm + m] = hph;
        ws[3 * Bb * Mm + b * Mm + m] = hpc;
    }
}

// ---------------------------------------------------------------------------
// Kernel 2 (v3): barrier-free streaming leaf. Swapped MFMA orientation:
//   D = Wt (A-op) x embs (B-op)  =>  D col(lane&15)=out-ROW, D row(4g+r)=out-COL
// so each lane's 4 acc regs are 4 contiguous out columns of one row -> direct
// f32x4 register stores, no LDS transpose, no epilogue barriers.
// embs B-frags load straight from global (lane ln owns row rowb+ln).
// W lives in LDS (64KB, XOR-swizzled: conflict-free ds_read_b128), staged once.
// 512 blocks x 512 thr = ALL resident (2 blocks/CU); 2 tiles/block,
// register-pipelined (tile1 loads issued before tile0 compute).
// ---------------------------------------------------------------------------
__global__ __launch_bounds__(512, 4)
void fused_kernel(const float* __restrict__ embs,
                  const short* __restrict__ wbf,
                  const float* __restrict__ bc, const float* __restrict__ bo,
                  const float* __restrict__ state,
                  float* __restrict__ out)
{
    __shared__ __align__(16) char smem[66560];
    char*  Wsw    = smem;                       // 64 KB swizzled bf16 W
    float* bias_l = (float*)(smem + 65536);     // [0..128)=bc, [128..256)=bo

    const int tid  = threadIdx.x;
    const int w    = tid >> 6;          // wave 0..7
    const int lane = tid & 63;
    const int g    = lane >> 4;         // lane group 0..3 (k-chunk)
    const int ln   = lane & 15;         // out-row-within-16 / W-col-within-16
    const int block_row = blockIdx.x * 256;
    const int b         = block_row >> 11;   // 8 blocks per batch, never spans

    // --- issue tile-0 embs loads immediately (latency hides under staging) --
    f32x4 e0[4], e1[4];
    {
        const float* erow = embs + (size_t)(block_row + w * 16 + ln) * Mm;
        #pragma unroll
        for (int ks = 0; ks < 4; ++ks) {
            e0[ks] = __builtin_nontemporal_load((const f32x4*)(erow + ks * 32 + g * 8));
            e1[ks] = __builtin_nontemporal_load((const f32x4*)(erow + ks * 32 + g * 8 + 4));
        }
    }

    // --- stage W into LDS, XOR-swizzled ------------------------------------
    // slot s (16B) = col256*16 + k8; LDS byte = col256*256 + ((k8^(col256&15))<<4)
    #pragma unroll
    for (int i = 0; i < 8; ++i) {
        int s = tid + 512 * i;                  // 0..4095
        bf16x8 v = *(const bf16x8*)(wbf + s * 8);
        int byteoff = ((s >> 4) << 8) | (((s & 15) ^ ((s >> 4) & 15)) << 4);
        *(bf16x8*)(Wsw + byteoff) = v;
    }
    if (tid < 256) bias_l[tid] = (tid < 128) ? bc[tid] : bo[tid - 128];

    // --- broadcast state values in regs (per-lane fixed cols: (lane>>1)*4) --
    f32x4 sv[4];
    #pragma unroll
    for (int s = 0; s < 4; ++s)
        sv[s] = *(const f32x4*)(state + s * (Bb * Mm) + b * Mm + (lane >> 1) * 4);

    __syncthreads();    // the ONLY block-wide barrier

    #pragma unroll
    for (int it = 0; it < 2; ++it) {
        const int rowb = block_row + it * 128 + w * 16;

        // pack this tile's B-fragments (k = ks*32 + g*8 + j)
        bf16x8 ef[4];
        #pragma unroll
        for (int ks = 0; ks < 4; ++ks) {
            bf16x8 f;
            f[0] = f2bf(e0[ks][0]); f[1] = f2bf(e0[ks][1]);
            f[2] = f2bf(e0[ks][2]); f[3] = f2bf(e0[ks][3]);
            f[4] = f2bf(e1[ks][0]); f[5] = f2bf(e1[ks][1]);
            f[6] = f2bf(e1[ks][2]); f[7] = f2bf(e1[ks][3]);
            ef[ks] = f;
        }
        if (it == 0) {  // issue tile-1 loads; latency hides under tile-0 work
            const float* erow = embs + (size_t)(rowb + 128 + ln) * Mm;
            #pragma unroll
            for (int ks = 0; ks < 4; ++ks) {
                e0[ks] = __builtin_nontemporal_load((const f32x4*)(erow + ks * 32 + g * 8));
                e1[ks] = __builtin_nontemporal_load((const f32x4*)(erow + ks * 32 + g * 8 + 4));
            }
        }

        float* orow = out + (size_t)(rowb + ln) * OUTC;

        // 8 col-chunk pairs: chunk cc (Wc cols cc*16..+16) + chunk 8+cc (Wo)
        #pragma unroll
        for (int cc = 0; cc < 8; ++cc) {
            f32x4 accc = *(const f32x4*)(bias_l + cc * 16 + g * 4);
            f32x4 acco = *(const f32x4*)(bias_l + 128 + cc * 16 + g * 4);
            #pragma unroll
            for (int ks = 0; ks < 4; ++ks) {
                const bf16x8* wp = (const bf16x8*)(Wsw +
                    (((cc * 16 + ln) << 8) | ((((ks * 4 + g) ^ ln)) << 4)));
                accc = __builtin_amdgcn_mfma_f32_16x16x32_bf16(
                    __builtin_bit_cast(bf16x8b, *wp),
                    __builtin_bit_cast(bf16x8b, ef[ks]), accc, 0, 0, 0);
            }
            #pragma unroll
            for (int ks = 0; ks < 4; ++ks) {
                const bf16x8* wp = (const bf16x8*)(Wsw +
                    (((128 + cc * 16 + ln) << 8) | ((((ks * 4 + g) ^ ln)) << 4)));
                acco = __builtin_amdgcn_mfma_f32_16x16x32_bf16(
                    __builtin_bit_cast(bf16x8b, *wp),
                    __builtin_bit_cast(bf16x8b, ef[ks]), acco, 0, 0, 0);
            }
            f32x4 hv;
            #pragma unroll
            for (int r = 0; r < 4; ++r)
                hv[r] = sigmoid_(acco[r]) * tanh_(accc[r]);
            *(f32x4*)(orow + cc * 16 + g * 4)       = accc;   // ce
            *(f32x4*)(orow + 384 + cc * 16 + g * 4) = hv;     // he
        }

        // broadcast sections: 2 full rows per instr (col-chunk = lane>>1)
        #pragma unroll
        for (int i = 0; i < 8; ++i) {
            float* br = out + (size_t)(rowb + 2 * i + (lane & 1)) * OUTC
                            + (lane >> 1) * 4;
            *(f32x4*)(br + 128) = sv[0];    // cph
            *(f32x4*)(br + 256) = sv[1];    // cpc
            *(f32x4*)(br + 512) = sv[2];    // hph
            *(f32x4*)(br + 640) = sv[3];    // hpc
        }
    }
}

extern "C" void kernel_launch(void* const* d_in, const int* in_sizes, int n_in,
                              void* d_out, int out_size, void* d_ws, size_t ws_size,
                              hipStream_t stream) {
    const float* embs   = (const float*)d_in[0];
    const float* root_c = (const float*)d_in[1];
    const float* root_h = (const float*)d_in[2];
    const float* Wi = (const float*)d_in[3];
    const float* bi = (const float*)d_in[4];
    const float* Wf = (const float*)d_in[5];
    const float* bfv= (const float*)d_in[6];
    const float* Wu = (const float*)d_in[7];
    const float* bu = (const float*)d_in[8];
    const float* Wc = (const float*)d_in[9];
    const float* bc = (const float*)d_in[10];
    const float* Wo = (const float*)d_in[11];
    const float* bo = (const float*)d_in[12];

    float* out   = (float*)d_out;
    float* state = (float*)d_ws;                       // 128 KB
    short* wbf   = (short*)d_ws + 65536;               // 64 KB bf16 W

    state_kernel<<<dim3(Bb), dim3(512), 0, stream>>>(
        root_c, root_h, Wi, bi, Wf, bfv, Wu, bu, Wc, bc, Wo, bo, state, wbf);
    fused_kernel<<<dim3(512), dim3(512), 0, stream>>>(
        embs, wbf, bc, bo, state, out);
}

// Round 6
// 115.609 us; speedup vs baseline: 1.0871x; 1.0871x over previous
//
#include <hip/hip_runtime.h>
#include <cstdint>
#include <cstddef>

// Problem constants
#define Bb   64
#define Ll   2048
#define Mm   128
#define ROWS (Bb * Ll)          // 131072
#define OUTC 768                // 6*M
#define LDA  136                // A-stage LDS stride (bf16 elems)
#define LDF  132                // epilogue LDS stride (f32 elems)

typedef __attribute__((ext_vector_type(4))) float  f32x4;
typedef __attribute__((ext_vector_type(8))) short  bf16x8;   // storage for 8 bf16
typedef __attribute__((ext_vector_type(4))) short  short4v;
typedef __bf16 bf16x8b __attribute__((ext_vector_type(8)));  // builtin operand type

__device__ __forceinline__ float rcp_(float x) {
#if __has_builtin(__builtin_amdgcn_rcpf)
    return __builtin_amdgcn_rcpf(x);
#else
    return 1.0f / x;
#endif
}
__device__ __forceinline__ float sigmoid_(float x) {
    return rcp_(1.0f + __expf(-x));
}
__device__ __forceinline__ float tanh_(float x) {
    float ax = fabsf(x);
    float r  = __expf(-2.0f * ax);
    float t  = (1.0f - r) * rcp_(1.0f + r);
    return x < 0.0f ? -t : t;
}
// f32 -> bf16 bits, round-to-nearest-even
__device__ __forceinline__ short f2bf(float f) {
    uint32_t u = __builtin_bit_cast(uint32_t, f);
    u = (u + 0x7FFFu + ((u >> 16) & 1u)) >> 16;
    return (short)(u & 0xFFFFu);
}

// LDS-only barrier (composable_kernel block_sync_lds pattern): waits LDS ops,
// does NOT drain vmcnt -> global stores + prefetch loads stay in flight.
__device__ __forceinline__ void lds_sync() {
    asm volatile("s_waitcnt lgkmcnt(0)\n\ts_barrier" ::: "memory");
}

// ---------------------------------------------------------------------------
// ws layout:
//   floats [0 .. 32768)     : state: [0]=cph,[1]=cpc,[2]=hph,[3]=hpc (64,128)
//   shorts [65536 .. 98304) : Wbf [gate*128+col][k] bf16, gate 0=Wc 1=Wo
// ---------------------------------------------------------------------------

// Kernel 1 (v3): collapsed tree state. Wi/Wf/Wu columns preloaded to registers
// (96 VGPR) so the 10 serial iterations are pure FMA + LDS-broadcast reads.
// k-split 4-way across 512 threads with LDS partial reduction; wprep fused.
__global__ __launch_bounds__(512)
void state_kernel(const float* __restrict__ root_c, const float* __restrict__ root_h,
                  const float* __restrict__ Wi, const float* __restrict__ bi,
                  const float* __restrict__ Wf, const float* __restrict__ bfv,
                  const float* __restrict__ Wu, const float* __restrict__ bu,
                  const float* __restrict__ Wc, const float* __restrict__ bc,
                  const float* __restrict__ Wo, const float* __restrict__ bo,
                  float* __restrict__ ws, short* __restrict__ wbf)
{
    const int b   = blockIdx.x;
    const int tid = threadIdx.x;
    const int m   = tid & 127;
    const int q   = tid >> 7;            // 0..3
    const int k0  = q * 32;

    __shared__ float h_sh[Mm];
    __shared__ float c_sh[Mm];
    __shared__ float part[4][4][Mm];     // [slot][q][m]

    // fused wprep: 64 blocks x 512 threads = 32768 elems, 1 per thread
    {
        int idx  = b * 512 + tid;
        int gate = idx >> 14;
        int col  = (idx >> 7) & 127;
        int k    = idx & 127;
        const float* W = gate ? Wo : Wc;
        wbf[idx] = f2bf(W[k * Mm + col]);
    }

    // preload my k-slice of Wi/Wf/Wu columns (coalesced across m)
    float wi[32], wf[32], wu[32];
    #pragma unroll
    for (int kk = 0; kk < 32; ++kk) {
        wi[kk] = Wi[(k0 + kk) * Mm + m];
        wf[kk] = Wf[(k0 + kk) * Mm + m];
        wu[kk] = Wu[(k0 + kk) * Mm + m];
    }

    float c = 0.f;
    if (q == 0) {
        c = root_c[b * Mm + m];
        h_sh[m] = root_h[b * Mm + m];
    }
    __syncthreads();

    const float bi_m = bi[m], bf_m = bfv[m], bu_m = bu[m];

    for (int it = 0; it < 10; ++it) {        // depth-1 = 10
        float di0 = 0.f, di1 = 0.f, df0 = 0.f, df1 = 0.f, du0 = 0.f, du1 = 0.f;
        #pragma unroll
        for (int kk = 0; kk < 32; kk += 2) {
            float h0 = h_sh[k0 + kk], h1 = h_sh[k0 + kk + 1];
            di0 = fmaf(h0, wi[kk], di0);
            di1 = fmaf(h1, wi[kk + 1], di1);
            df0 = fmaf(h0, wf[kk], df0);
            df1 = fmaf(h1, wf[kk + 1], df1);
            du0 = fmaf(h0, wu[kk], du0);
            du1 = fmaf(h1, wu[kk + 1], du1);
        }
        part[0][q][m] = di0 + di1;
        part[1][q][m] = df0 + df1;
        part[2][q][m] = du0 + du1;
        __syncthreads();
        if (q == 0) {
            float di = (part[0][0][m] + part[0][1][m]) + (part[0][2][m] + part[0][3][m]);
            float df = (part[1][0][m] + part[1][1][m]) + (part[1][2][m] + part[1][3][m]);
            float du = (part[2][0][m] + part[2][1][m]) + (part[2][2][m] + part[2][3][m]);
            float ig = sigmoid_(di + bi_m);
            float fg = sigmoid_(df + bf_m);
            float ug = tanh_(du + bu_m);
            c = ig * ug + fg * c;
            h_sh[m] = tanh_(c);
        }
        __syncthreads();
    }
    if (q == 0) c_sh[m] = c;
    __syncthreads();

    // leaf on final h and c states, k-split (one-shot, stream Wc/Wo from L2)
    float dch = 0.f, doh = 0.f, dcc = 0.f, doc = 0.f;
    #pragma unroll
    for (int kk = 0; kk < 32; ++kk) {
        int k = k0 + kk;
        float hk = h_sh[k], ck = c_sh[k];
        float wc = Wc[k * Mm + m], wo = Wo[k * Mm + m];
        dch = fmaf(hk, wc, dch);
        doh = fmaf(hk, wo, doh);
        dcc = fmaf(ck, wc, dcc);
        doc = fmaf(ck, wo, doc);
    }
    part[0][q][m] = dch;
    part[1][q][m] = doh;
    part[2][q][m] = dcc;
    part[3][q][m] = doc;
    __syncthreads();
    if (q == 0) {
        float Dch = (part[0][0][m] + part[0][1][m]) + (part[0][2][m] + part[0][3][m]);
        float Doh = (part[1][0][m] + part[1][1][m]) + (part[1][2][m] + part[1][3][m]);
        float Dcc = (part[2][0][m] + part[2][1][m]) + (part[2][2][m] + part[2][3][m]);
        float Doc = (part[3][0][m] + part[3][1][m]) + (part[3][2][m] + part[3][3][m]);
        const float bcm = bc[m], bom = bo[m];
        float cph = Dch + bcm;
        float cpc = Dcc + bcm;
        float hph = sigmoid_(Doh + bom) * tanh_(cph);
        float hpc = sigmoid_(Doc + bom) * tanh_(cpc);
        ws[0 * Bb * Mm + b * Mm + m] = cph;
        ws[1 * Bb * Mm + b * Mm + m] = cpc;
        ws[2 * Bb * Mm + b * Mm + m] = hph;
        ws[3 * Bb * Mm + b * Mm + m] = hpc;
    }
}

// ---------------------------------------------------------------------------
// Kernel 2 (v4 = R4 skeleton + lgkm-only barriers + 4-tile pipeline):
// 512 blocks x 512 thr (8 waves), 4 tiles of 64 rows per block, A double-
// buffered in LDS. All syncs are lds_sync() (no vmcnt drain) -> stores stream
// across tile boundaries, prefetch loads stay in flight. Broadcast sections
// (268MB) stored register-sourced, barrier-free. ce/he transposed through LDS
// for fully-coalesced 512B row segments.
// ---------------------------------------------------------------------------
__global__ __launch_bounds__(512, 4)
void fused_kernel(const float* __restrict__ embs,
                  const short* __restrict__ wbf,
                  const float* __restrict__ bc, const float* __restrict__ bo,
                  const float* __restrict__ state,
                  float* __restrict__ out)
{
    // A0[64][LDA]bf16 | A1[64][LDA]bf16 | ce[32][LDF]f32 | he[32][LDF]f32 | st[4][128]
    __shared__ __align__(16) char smem[70656];
    short* A0   = (short*)smem;                    // 17408 B
    short* A1   = (short*)(smem + 17408);          // 17408 B
    float* ce_l = (float*)(smem + 34816);          // 16896 B
    float* he_l = (float*)(smem + 51712);          // 16896 B
    float* st_l = (float*)(smem + 68608);          // 2048 B

    const int tid  = threadIdx.x;
    const int w    = tid >> 6;          // wave 0..7
    const int lane = tid & 63;
    const int g    = lane >> 4;         // lane group 0..3
    const int ln   = lane & 15;
    const int n0   = w * 16 + ln;       // output col 0..127
    const int block_row = blockIdx.x * 256;     // 4 tiles x 64 rows
    const int b         = block_row >> 11;      // 8 blocks/batch, never spans

    // --- B fragments + biases + state stash ---------------------------------
    bf16x8 bfrag[2][4];                 // [gate][ks], k = ks*32 + g*8 + j
    #pragma unroll
    for (int gate = 0; gate < 2; ++gate)
        #pragma unroll
        for (int ks = 0; ks < 4; ++ks)
            bfrag[gate][ks] = *(const bf16x8*)(
                wbf + gate * (Mm * Mm) + n0 * Mm + ks * 32 + g * 8);
    const float biasc = bc[n0];
    const float biaso = bo[n0];
    st_l[tid] = state[(tid >> 7) * (Bb * Mm) + b * Mm + (tid & 127)];

    // helpers ----------------------------------------------------------------
    auto stage_load = [&](int rb, f32x4 (&r)[4]) {
        #pragma unroll
        for (int i = 0; i < 4; ++i) {
            int idx = tid + 512 * i;            // 0..2047 float4-slots
            int rr  = idx >> 5;
            int kq  = idx & 31;
            r[i] = __builtin_nontemporal_load(
                (const f32x4*)(embs + (size_t)(rb + rr) * Mm + kq * 4));
        }
    };
    auto stage_write = [&](short* A, const f32x4 (&r)[4]) {
        #pragma unroll
        for (int i = 0; i < 4; ++i) {
            int idx = tid + 512 * i;
            int rr  = idx >> 5;
            int kq  = idx & 31;
            short4v s4;
            s4[0] = f2bf(r[i][0]); s4[1] = f2bf(r[i][1]);
            s4[2] = f2bf(r[i][2]); s4[3] = f2bf(r[i][3]);
            *(short4v*)(&A[rr * LDA + kq * 4]) = s4;
        }
    };

    // --- prologue: stage tile 0 ---------------------------------------------
    f32x4 r[4];
    stage_load(block_row, r);
    stage_write(A0, r);
    lds_sync();

    for (int t = 0; t < 4; ++t) {
        const int rowbase = block_row + t * 64;
        const short* Acur = (t & 1) ? A1 : A0;
        short*       Anxt = (t & 1) ? A0 : A1;

        // issue next tile's loads before compute (latency hides under MFMA)
        if (t < 3) stage_load(rowbase + 64, r);

        // --- MFMA: 4 row-subtiles x 2 gates x 4 k-steps ---------------------
        f32x4 acc[4][2];
        #pragma unroll
        for (int rt = 0; rt < 4; ++rt)
            #pragma unroll
            for (int gate = 0; gate < 2; ++gate) {
                float bv = gate ? biaso : biasc;
                acc[rt][gate][0] = bv; acc[rt][gate][1] = bv;
                acc[rt][gate][2] = bv; acc[rt][gate][3] = bv;
            }
        #pragma unroll
        for (int ks = 0; ks < 4; ++ks) {
            bf16x8 af[4];
            #pragma unroll
            for (int rt = 0; rt < 4; ++rt)
                af[rt] = *(const bf16x8*)(&Acur[(rt * 16 + ln) * LDA + ks * 32 + g * 8]);
            #pragma unroll
            for (int rt = 0; rt < 4; ++rt)
                #pragma unroll
                for (int gate = 0; gate < 2; ++gate)
                    acc[rt][gate] = __builtin_amdgcn_mfma_f32_16x16x32_bf16(
                        __builtin_bit_cast(bf16x8b, af[rt]),
                        __builtin_bit_cast(bf16x8b, bfrag[gate][ks]),
                        acc[rt][gate], 0, 0, 0);
        }

        // stage next tile into the other buffer (read for t+1 after end-sync)
        if (t < 3) stage_write(Anxt, r);

        // --- epilogue: 2 halves; D layout col=lane&15(n0), row=4g+reg -------
        #pragma unroll
        for (int half = 0; half < 2; ++half) {
            #pragma unroll
            for (int qq = 0; qq < 2; ++qq) {
                int rt = half * 2 + qq;
                #pragma unroll
                for (int rr = 0; rr < 4; ++rr) {
                    int rowL = qq * 16 + g * 4 + rr;     // 0..31 in this half
                    float cv = acc[rt][0][rr];
                    float hv = sigmoid_(acc[rt][1][rr]) * tanh_(cv);
                    ce_l[rowL * LDF + n0] = cv;
                    he_l[rowL * LDF + n0] = hv;
                }
            }
            lds_sync();
            // 32 rows x 64 f32x4 (ce|he) = 2048 units, 4/thread, 512B segments
            #pragma unroll
            for (int i = 0; i < 4; ++i) {
                int u   = tid + 512 * i;
                int rg  = u >> 6;
                int s   = u & 63;
                int sec = s >> 5;           // 0:ce  1:he
                int cc  = s & 31;
                const float* src = (sec ? he_l : ce_l) + rg * LDF + cc * 4;
                f32x4 v = *(const f32x4*)src;
                *(f32x4*)(out + (size_t)(rowbase + half * 32 + rg) * OUTC
                              + sec * 384 + cc * 4) = v;
            }
            if (half == 0) lds_sync();      // reads done before half1 writes
        }

        // --- broadcast sections: barrier-free, 2 rows x 512B per instr ------
        {
            int c4 = (tid & 31) * 4;
            int rw = tid >> 5;              // 0..15
            f32x4 s0 = *(const f32x4*)(st_l + 0 * 128 + c4);
            f32x4 s1 = *(const f32x4*)(st_l + 1 * 128 + c4);
            f32x4 s2 = *(const f32x4*)(st_l + 2 * 128 + c4);
            f32x4 s3 = *(const f32x4*)(st_l + 3 * 128 + c4);
            #pragma unroll
            for (int j = 0; j < 4; ++j) {
                float* br = out + (size_t)(rowbase + rw + 16 * j) * OUTC + c4;
                *(f32x4*)(br + 128) = s0;   // cph
                *(f32x4*)(br + 256) = s1;   // cpc
                *(f32x4*)(br + 512) = s2;   // hph
                *(f32x4*)(br + 640) = s3;   // hpc
            }
        }

        lds_sync();   // end of tile: half1 reads done, Anxt visible, Acur free
    }
}

extern "C" void kernel_launch(void* const* d_in, const int* in_sizes, int n_in,
                              void* d_out, int out_size, void* d_ws, size_t ws_size,
                              hipStream_t stream) {
    const float* embs   = (const float*)d_in[0];
    const float* root_c = (const float*)d_in[1];
    const float* root_h = (const float*)d_in[2];
    const float* Wi = (const float*)d_in[3];
    const float* bi = (const float*)d_in[4];
    const float* Wf = (const float*)d_in[5];
    const float* bfv= (const float*)d_in[6];
    const float* Wu = (const float*)d_in[7];
    const float* bu = (const float*)d_in[8];
    const float* Wc = (const float*)d_in[9];
    const float* bc = (const float*)d_in[10];
    const float* Wo = (const float*)d_in[11];
    const float* bo = (const float*)d_in[12];

    float* out   = (float*)d_out;
    float* state = (float*)d_ws;                       // 128 KB
    short* wbf   = (short*)d_ws + 65536;               // 64 KB bf16 W

    state_kernel<<<dim3(Bb), dim3(512), 0, stream>>>(
        root_c, root_h, Wi, bi, Wf, bfv, Wu, bu, Wc, bc, Wo, bo, state, wbf);
    fused_kernel<<<dim3(512), dim3(512), 0, stream>>>(
        embs, wbf, bc, bo, state, out);
}

// Round 7
// 109.827 us; speedup vs baseline: 1.1443x; 1.0526x over previous
//
#include <hip/hip_runtime.h>
#include <cstdint>
#include <cstddef>

// Problem constants
#define Bb   64
#define Ll   2048
#define Mm   128
#define ROWS (Bb * Ll)          // 131072
#define OUTC 768                // 6*M
#define LDA  136                // A-stage LDS stride (bf16 elems)
#define LDF  132                // epilogue LDS stride (f32 elems)

typedef __attribute__((ext_vector_type(4))) float  f32x4;
typedef __attribute__((ext_vector_type(8))) short  bf16x8;   // storage for 8 bf16
typedef __attribute__((ext_vector_type(4))) short  short4v;
typedef __bf16 bf16x8b __attribute__((ext_vector_type(8)));  // builtin operand type

__device__ __forceinline__ float rcp_(float x) {
#if __has_builtin(__builtin_amdgcn_rcpf)
    return __builtin_amdgcn_rcpf(x);
#else
    return 1.0f / x;
#endif
}
__device__ __forceinline__ float sigmoid_(float x) {
    return rcp_(1.0f + __expf(-x));
}
__device__ __forceinline__ float tanh_(float x) {
    float ax = fabsf(x);
    float r  = __expf(-2.0f * ax);
    float t  = (1.0f - r) * rcp_(1.0f + r);
    return x < 0.0f ? -t : t;
}
// f32 -> bf16 bits, round-to-nearest-even
__device__ __forceinline__ short f2bf(float f) {
    uint32_t u = __builtin_bit_cast(uint32_t, f);
    u = (u + 0x7FFFu + ((u >> 16) & 1u)) >> 16;
    return (short)(u & 0xFFFFu);
}

// LDS-only barrier (composable_kernel block_sync_lds pattern): waits LDS ops,
// does NOT drain vmcnt -> global stores + prefetch loads stay in flight.
__device__ __forceinline__ void lds_sync() {
    asm volatile("s_waitcnt lgkmcnt(0)\n\ts_barrier" ::: "memory");
}

// ---------------------------------------------------------------------------
// ws layout:
//   floats [0 .. 32768)     : state: [0]=cph,[1]=cpc,[2]=hph,[3]=hpc (64,128)
//   shorts [65536 .. 98304) : Wbf [gate*128+col][k] bf16, gate 0=Wc 1=Wo
// ---------------------------------------------------------------------------

// Kernel 1 (v3): collapsed tree state. Wi/Wf/Wu columns preloaded to registers
// so the 10 serial iterations are pure FMA + LDS-broadcast reads.
// k-split 4-way across 512 threads with LDS partial reduction; wprep fused.
__global__ __launch_bounds__(512)
void state_kernel(const float* __restrict__ root_c, const float* __restrict__ root_h,
                  const float* __restrict__ Wi, const float* __restrict__ bi,
                  const float* __restrict__ Wf, const float* __restrict__ bfv,
                  const float* __restrict__ Wu, const float* __restrict__ bu,
                  const float* __restrict__ Wc, const float* __restrict__ bc,
                  const float* __restrict__ Wo, const float* __restrict__ bo,
                  float* __restrict__ ws, short* __restrict__ wbf)
{
    const int b   = blockIdx.x;
    const int tid = threadIdx.x;
    const int m   = tid & 127;
    const int q   = tid >> 7;            // 0..3
    const int k0  = q * 32;

    __shared__ float h_sh[Mm];
    __shared__ float c_sh[Mm];
    __shared__ float part[4][4][Mm];     // [slot][q][m]

    // fused wprep: 64 blocks x 512 threads = 32768 elems, 1 per thread
    {
        int idx  = b * 512 + tid;
        int gate = idx >> 14;
        int col  = (idx >> 7) & 127;
        int k    = idx & 127;
        const float* W = gate ? Wo : Wc;
        wbf[idx] = f2bf(W[k * Mm + col]);
    }

    // preload my k-slice of Wi/Wf/Wu columns (coalesced across m)
    float wi[32], wf[32], wu[32];
    #pragma unroll
    for (int kk = 0; kk < 32; ++kk) {
        wi[kk] = Wi[(k0 + kk) * Mm + m];
        wf[kk] = Wf[(k0 + kk) * Mm + m];
        wu[kk] = Wu[(k0 + kk) * Mm + m];
    }

    float c = 0.f;
    if (q == 0) {
        c = root_c[b * Mm + m];
        h_sh[m] = root_h[b * Mm + m];
    }
    __syncthreads();

    const float bi_m = bi[m], bf_m = bfv[m], bu_m = bu[m];

    for (int it = 0; it < 10; ++it) {        // depth-1 = 10
        float di0 = 0.f, di1 = 0.f, df0 = 0.f, df1 = 0.f, du0 = 0.f, du1 = 0.f;
        #pragma unroll
        for (int kk = 0; kk < 32; kk += 2) {
            float h0 = h_sh[k0 + kk], h1 = h_sh[k0 + kk + 1];
            di0 = fmaf(h0, wi[kk], di0);
            di1 = fmaf(h1, wi[kk + 1], di1);
            df0 = fmaf(h0, wf[kk], df0);
            df1 = fmaf(h1, wf[kk + 1], df1);
            du0 = fmaf(h0, wu[kk], du0);
            du1 = fmaf(h1, wu[kk + 1], du1);
        }
        part[0][q][m] = di0 + di1;
        part[1][q][m] = df0 + df1;
        part[2][q][m] = du0 + du1;
        __syncthreads();
        if (q == 0) {
            float di = (part[0][0][m] + part[0][1][m]) + (part[0][2][m] + part[0][3][m]);
            float df = (part[1][0][m] + part[1][1][m]) + (part[1][2][m] + part[1][3][m]);
            float du = (part[2][0][m] + part[2][1][m]) + (part[2][2][m] + part[2][3][m]);
            float ig = sigmoid_(di + bi_m);
            float fg = sigmoid_(df + bf_m);
            float ug = tanh_(du + bu_m);
            c = ig * ug + fg * c;
            h_sh[m] = tanh_(c);
        }
        __syncthreads();
    }
    if (q == 0) c_sh[m] = c;
    __syncthreads();

    // leaf on final h and c states, k-split
    float dch = 0.f, doh = 0.f, dcc = 0.f, doc = 0.f;
    #pragma unroll
    for (int kk = 0; kk < 32; ++kk) {
        int k = k0 + kk;
        float hk = h_sh[k], ck = c_sh[k];
        float wc = Wc[k * Mm + m], wo = Wo[k * Mm + m];
        dch = fmaf(hk, wc, dch);
        doh = fmaf(hk, wo, doh);
        dcc = fmaf(ck, wc, dcc);
        doc = fmaf(ck, wo, doc);
    }
    part[0][q][m] = dch;
    part[1][q][m] = doh;
    part[2][q][m] = dcc;
    part[3][q][m] = doc;
    __syncthreads();
    if (q == 0) {
        float Dch = (part[0][0][m] + part[0][1][m]) + (part[0][2][m] + part[0][3][m]);
        float Doh = (part[1][0][m] + part[1][1][m]) + (part[1][2][m] + part[1][3][m]);
        float Dcc = (part[2][0][m] + part[2][1][m]) + (part[2][2][m] + part[2][3][m]);
        float Doc = (part[3][0][m] + part[3][1][m]) + (part[3][2][m] + part[3][3][m]);
        const float bcm = bc[m], bom = bo[m];
        float cph = Dch + bcm;
        float cpc = Dcc + bcm;
        float hph = sigmoid_(Doh + bom) * tanh_(cph);
        float hpc = sigmoid_(Doc + bom) * tanh_(cpc);
        ws[0 * Bb * Mm + b * Mm + m] = cph;
        ws[1 * Bb * Mm + b * Mm + m] = cpc;
        ws[2 * Bb * Mm + b * Mm + m] = hph;
        ws[3 * Bb * Mm + b * Mm + m] = hpc;
    }
}

// ---------------------------------------------------------------------------
// Kernel 2 (v5 = R4 skeleton verbatim, with lgkm-only barriers):
// 1024 blocks x 512 thr, 2 tiles of 64 rows/block, A double-buffered in LDS,
// unified full-row epilogue (each row's 3KB written once, ascending).
// All syncs are lds_sync() -> global stores stream across barriers and
// prefetch loads stay in flight (no vmcnt(0) drains inside the kernel).
// ---------------------------------------------------------------------------
__global__ __launch_bounds__(512, 4)
void fused_kernel(const float* __restrict__ embs,
                  const short* __restrict__ wbf,
                  const float* __restrict__ bc, const float* __restrict__ bo,
                  const float* __restrict__ state,
                  float* __restrict__ out)
{
    // A0[64][LDA]bf16 | A1[64][LDA]bf16 | ce[32][LDF]f32 | he[32][LDF]f32 | st[4][128]
    __shared__ __align__(16) char smem[70656];
    short* A0   = (short*)smem;                    // 17408 B
    short* A1   = (short*)(smem + 17408);          // 17408 B
    float* ce_l = (float*)(smem + 34816);          // 16896 B
    float* he_l = (float*)(smem + 51712);          // 16896 B
    float* st_l = (float*)(smem + 68608);          // 2048 B

    const int tid  = threadIdx.x;
    const int w    = tid >> 6;          // wave 0..7
    const int lane = tid & 63;
    const int g    = lane >> 4;         // lane group 0..3
    const int ln   = lane & 15;
    const int n0   = w * 16 + ln;       // output col 0..127
    const int rowbase0 = blockIdx.x * 128;
    const int rowbase1 = rowbase0 + 64;
    const int b        = rowbase0 >> 11;   // 128 | 2048, never spans batches

    // --- B fragments + biases + state stash (fly during staging) -----------
    bf16x8 bfrag[2][4];                 // [gate][ks], k = ks*32 + g*8 + j
    #pragma unroll
    for (int gate = 0; gate < 2; ++gate)
        #pragma unroll
        for (int ks = 0; ks < 4; ++ks)
            bfrag[gate][ks] = *(const bf16x8*)(
                wbf + gate * (Mm * Mm) + n0 * Mm + ks * 32 + g * 8);
    const float biasc = bc[n0];
    const float biaso = bo[n0];
    st_l[tid] = state[(tid >> 7) * (Bb * Mm) + b * Mm + (tid & 127)];

    // helpers ---------------------------------------------------------------
    auto stage_load = [&](int rowbase, f32x4 (&r)[4]) {
        #pragma unroll
        for (int i = 0; i < 4; ++i) {
            int idx = tid + 512 * i;            // 0..2047 float4-slots
            int rr  = idx >> 5;
            int kq  = idx & 31;
            r[i] = __builtin_nontemporal_load(
                (const f32x4*)(embs + (size_t)(rowbase + rr) * Mm + kq * 4));
        }
    };
    auto stage_write = [&](short* A, const f32x4 (&r)[4]) {
        #pragma unroll
        for (int i = 0; i < 4; ++i) {
            int idx = tid + 512 * i;
            int rr  = idx >> 5;
            int kq  = idx & 31;
            short4v s4;
            s4[0] = f2bf(r[i][0]); s4[1] = f2bf(r[i][1]);
            s4[2] = f2bf(r[i][2]); s4[3] = f2bf(r[i][3]);
            *(short4v*)(&A[rr * LDA + kq * 4]) = s4;
        }
    };
    auto do_mfma = [&](const short* A, f32x4 (&acc)[4][2]) {
        #pragma unroll
        for (int rt = 0; rt < 4; ++rt)
            #pragma unroll
            for (int gate = 0; gate < 2; ++gate) {
                float bv = gate ? biaso : biasc;
                acc[rt][gate][0] = bv; acc[rt][gate][1] = bv;
                acc[rt][gate][2] = bv; acc[rt][gate][3] = bv;
            }
        #pragma unroll
        for (int ks = 0; ks < 4; ++ks) {
            bf16x8 af[4];
            #pragma unroll
            for (int rt = 0; rt < 4; ++rt)
                af[rt] = *(const bf16x8*)(&A[(rt * 16 + ln) * LDA + ks * 32 + g * 8]);
            #pragma unroll
            for (int rt = 0; rt < 4; ++rt)
                #pragma unroll
                for (int gate = 0; gate < 2; ++gate)
                    acc[rt][gate] = __builtin_amdgcn_mfma_f32_16x16x32_bf16(
                        __builtin_bit_cast(bf16x8b, af[rt]),
                        __builtin_bit_cast(bf16x8b, bfrag[gate][ks]),
                        acc[rt][gate], 0, 0, 0);
        }
    };
    // epilogue: D layout col = lane&15 (= n0), row = 4*(lane>>4) + reg;
    // unified full-row writes: every row's 3KB stored once, ascending order.
    auto epilogue = [&](int rowbase, f32x4 (&acc)[4][2]) {
        #pragma unroll
        for (int half = 0; half < 2; ++half) {
            #pragma unroll
            for (int qq = 0; qq < 2; ++qq) {
                int rt = half * 2 + qq;
                #pragma unroll
                for (int r = 0; r < 4; ++r) {
                    int rowL = qq * 16 + g * 4 + r;      // 0..31 in this half
                    float cv = acc[rt][0][r];
                    float hv = sigmoid_(acc[rt][1][r]) * tanh_(cv);
                    ce_l[rowL * LDF + n0] = cv;
                    he_l[rowL * LDF + n0] = hv;
                }
            }
            lds_sync();
            // 32 rows x 192 f32x4 = 6144 units; 12/thread; lanes contiguous
            #pragma unroll
            for (int i = 0; i < 12; ++i) {
                int u  = tid + 512 * i;
                int rg = u / 192;
                int s  = u - rg * 192;      // f32x4 col in row, 0..191
                int sec = s >> 5;           // 0:ce 1:cph 2:cpc 3:he 4:hph 5:hpc
                int cc  = s & 31;
                const float* src =
                    (sec == 0) ? (ce_l + rg * LDF + cc * 4) :
                    (sec == 3) ? (he_l + rg * LDF + cc * 4) :
                    (st_l + ((sec < 3) ? (sec - 1) : (sec - 2)) * 128 + cc * 4);
                f32x4 v = *(const f32x4*)src;
                *(f32x4*)(out + (size_t)(rowbase + half * 32 + rg) * OUTC + s * 4) = v;
            }
            lds_sync();                     // LDS reads done before reuse
        }
    };

    // --- pipeline ----------------------------------------------------------
    f32x4 r0[4], r1[4];
    f32x4 acc[4][2];

    stage_load(rowbase0, r0);
    stage_write(A0, r0);
    lds_sync();                             // A0 visible (LDS-only wait)

    stage_load(rowbase1, r1);               // t1 reads in flight under t0 work

    do_mfma(A0, acc);
    stage_write(A1, r1);                    // reg-use vmcnt wait sits here
    lds_sync();                             // A0 reads done; A1 visible

    epilogue(rowbase0, acc);                // stores stream, no vmcnt drain
    do_mfma(A1, acc);
    epilogue(rowbase1, acc);
}

extern "C" void kernel_launch(void* const* d_in, const int* in_sizes, int n_in,
                              void* d_out, int out_size, void* d_ws, size_t ws_size,
                              hipStream_t stream) {
    const float* embs   = (const float*)d_in[0];
    const float* root_c = (const float*)d_in[1];
    const float* root_h = (const float*)d_in[2];
    const float* Wi = (const float*)d_in[3];
    const float* bi = (const float*)d_in[4];
    const float* Wf = (const float*)d_in[5];
    const float* bfv= (const float*)d_in[6];
    const float* Wu = (const float*)d_in[7];
    const float* bu = (const float*)d_in[8];
    const float* Wc = (const float*)d_in[9];
    const float* bc = (const float*)d_in[10];
    const float* Wo = (const float*)d_in[11];
    const float* bo = (const float*)d_in[12];

    float* out   = (float*)d_out;
    float* state = (float*)d_ws;                       // 128 KB
    short* wbf   = (short*)d_ws + 65536;               // 64 KB bf16 W

    state_kernel<<<dim3(Bb), dim3(512), 0, stream>>>(
        root_c, root_h, Wi, bi, Wf, bfv, Wu, bu, Wc, bc, Wo, bo, state, wbf);
    fused_kernel<<<dim3(1024), dim3(512), 0, stream>>>(
        embs, wbf, bc, bo, state, out);
}